// Round 3
// baseline (1170.618 us; speedup 1.0000x reference)
//
#include <hip/hip_runtime.h>
#include <hip/hip_fp16.h>

#define NN 50000
#define EE 800000
#define ET 850000          // EE + NN self-loops
#define NEG 0.2f
#define GRID 768
#define SCAN_B 1024
#define NBLK 49            // ceil(NN / SCAN_B)
#define GT1 782            // gemm 64-row tiles over 50000 rows
#define S1A 480            // gemm1 tiles in P1 (|| hist)
#define S1B 530            // .. through P2 (|| scan1)
#define S1C 580            // .. through P3 (|| scan23); rest in P4 (|| scatter)
#define HB 3321            // edge passes: ceil(ET/256) virtual blocks
#define AGG_VB 6250        // NN/8 agg virtual blocks
#define ASPL 4096          // agg1 split: vb [0,4096) = nodes [0,32768)
#define NSPL 32768
#define G2A 512            // gemm2 tiles covering rows [0,32768)

__device__ __forceinline__ float leaky(float x) { return fmaxf(x, NEG * x); }
__device__ __forceinline__ float elu_f(float x) { return x > 0.f ? x : expm1f(x); }

struct alignas(8) half4 { __half2 a, b; };

typedef _Float16 half8_t __attribute__((ext_vector_type(8)));
typedef float float4_t __attribute__((ext_vector_type(4)));

struct Params {
    const float *x; const int *ei;
    const float *W1, *as1, *ad1, *b1;
    const float *W2, *as2, *ad2, *b2;
    const float *W3, *s3w, *d3w, *b3;
    float *out;
    __half *hA, *hBh, *hC, *Wt1, *Wt2;
    float *asb, *adb, *asb2, *adb2;
    int *rp, *counts, *csr, *rank, *bsums;
    float *h3, *s3v, *d3v;
    int *cnt, *rel;
};

// ---- grid-wide barrier: all GRID blocks co-resident (launch_bounds(256,4)
// guarantees >=4 blocks/CU capacity; 768 = 3x256). Agent-scope atomics so the
// spin load bypasses the non-coherent per-XCD L2; __threadfence gives the
// device-scope release/acquire cache ops around the signal.
__device__ __forceinline__ void gsync(int* cnt, int* rel, int ph) {
    __syncthreads();
    if (threadIdx.x == 0) {
        __threadfence();   // release: write back this XCD's dirty lines
        int old = __hip_atomic_fetch_add(cnt, 1, __ATOMIC_ACQ_REL, __HIP_MEMORY_SCOPE_AGENT);
        if (old == GRID - 1) {
            __hip_atomic_store(cnt, 0, __ATOMIC_RELAXED, __HIP_MEMORY_SCOPE_AGENT);
            __hip_atomic_store(rel, ph, __ATOMIC_RELEASE, __HIP_MEMORY_SCOPE_AGENT);
        } else {
            while (__hip_atomic_load(rel, __ATOMIC_RELAXED, __HIP_MEMORY_SCOPE_AGENT) < ph)
                __builtin_amdgcn_s_sleep(8);
        }
        __threadfence();   // acquire: invalidate stale L1/L2
    }
    __syncthreads();
}

// ---- MFMA GEMM tile: 16 rows x 128 cols per wave, fused attention logits ----
__device__ __forceinline__
void gemm_tile(const float* __restrict__ Xf, const __half* __restrict__ Xh,
               const __half* __restrict__ Wt, __half* __restrict__ Yh,
               int nrows, int row0, int lane,
               const float* __restrict__ att_s, const float* __restrict__ att_d,
               float* __restrict__ asb, float* __restrict__ adb) {
    int n = lane & 15, quad = lane >> 4;
    float atts_r[8], attd_r[8];
#pragma unroll
    for (int t = 0; t < 8; ++t) {
        atts_r[t] = att_s[t * 16 + n];
        attd_r[t] = att_d[t * 16 + n];
    }
    float4_t acc[8];
#pragma unroll
    for (int t = 0; t < 8; ++t) acc[t] = (float4_t){0.f, 0.f, 0.f, 0.f};
    int rA = row0 + n; if (rA >= nrows) rA = nrows - 1;
#pragma unroll
    for (int ch = 0; ch < 4; ++ch) {
        half8_t a;
        if (Xh) {
            a = *(const half8_t*)(Xh + (size_t)rA * 128 + ch * 32 + quad * 8);
        } else {
            const float* xp = Xf + (size_t)rA * 128 + ch * 32 + quad * 8;
            float4 f0 = *(const float4*)xp;
            float4 f1 = *(const float4*)(xp + 4);
            a = (half8_t){(_Float16)f0.x, (_Float16)f0.y, (_Float16)f0.z, (_Float16)f0.w,
                          (_Float16)f1.x, (_Float16)f1.y, (_Float16)f1.z, (_Float16)f1.w};
        }
#pragma unroll
        for (int t = 0; t < 8; ++t) {
            half8_t b = *(const half8_t*)(Wt + (t * 16 + n) * 128 + ch * 32 + quad * 8);
            acc[t] = __builtin_amdgcn_mfma_f32_16x16x32_f16(a, b, acc[t], 0, 0, 0);
        }
    }
#pragma unroll
    for (int rg = 0; rg < 4; ++rg) {
        int row = row0 + quad * 4 + rg;
        if (row < nrows) {
            __half* yp = Yh + (size_t)row * 128 + n;
#pragma unroll
            for (int t = 0; t < 8; ++t)
                yp[t * 16] = __float2half(acc[t][rg]);
        }
    }
#pragma unroll
    for (int rg = 0; rg < 4; ++rg) {
        float ps[4], pd[4];
#pragma unroll
        for (int h = 0; h < 4; ++h) {
            ps[h] = acc[2*h][rg] * atts_r[2*h] + acc[2*h+1][rg] * atts_r[2*h+1];
            pd[h] = acc[2*h][rg] * attd_r[2*h] + acc[2*h+1][rg] * attd_r[2*h+1];
#pragma unroll
            for (int mask = 1; mask < 16; mask <<= 1) {
                ps[h] += __shfl_xor(ps[h], mask, 64);
                pd[h] += __shfl_xor(pd[h], mask, 64);
            }
        }
        int row = row0 + quad * 4 + rg;
        if (n == 0 && row < nrows) {
#pragma unroll
            for (int h = 0; h < 4; ++h) {
                asb[row * 4 + h] = ps[h];
                adb[row * 4 + h] = pd[h];
            }
        }
    }
}

// ---- per-node softmax + aggregation (half-wave = 32 lanes per node) ----
__device__ __forceinline__
void agg_node(int n, int l, const __half* __restrict__ Hh,
              const float* __restrict__ asb, const float* __restrict__ adb,
              const int* __restrict__ rp, const int* __restrict__ csr,
              const float* __restrict__ bias, __half* __restrict__ Y,
              const float* __restrict__ W3, const float* __restrict__ s3w,
              const float* __restrict__ d3w, float* __restrict__ h3,
              float* __restrict__ as3, float* __restrict__ ad3) {
    if (n >= NN) return;
    int hd = l >> 3;
    float ad = adb[n * 4 + hd];
    float acc0 = 0.f, acc1 = 0.f, acc2 = 0.f, acc3 = 0.f, den = 0.f;
    int e = rp[n], end = rp[n + 1], last = end - 1;
    for (int base = e; base < end; base += 8) {
        int s[8]; float a[8]; float2 hraw[8];
#pragma unroll
        for (int j = 0; j < 8; ++j) {
            int i = base + j;
            s[j] = csr[i <= last ? i : last];
        }
#pragma unroll
        for (int j = 0; j < 8; ++j) a[j] = asb[s[j] * 4 + hd] + ad;
#pragma unroll
        for (int j = 0; j < 8; ++j)
            hraw[j] = ((const float2*)(Hh + (size_t)s[j] * 128))[l];
#pragma unroll
        for (int j = 0; j < 8; ++j) {
            float w = __expf(leaky(a[j]));
            w = (base + j <= last) ? w : 0.f;
            den += w;
            const __half2* hp = (const __half2*)&hraw[j];
            float2 f01 = __half22float2(hp[0]);
            float2 f23 = __half22float2(hp[1]);
            acc0 += w * f01.x; acc1 += w * f01.y;
            acc2 += w * f23.x; acc3 += w * f23.y;
        }
    }
    float4 bv = ((const float4*)bias)[l];
    float inv = 1.f / den;
    float o0 = elu_f(acc0 * inv + bv.x);
    float o1 = elu_f(acc1 * inv + bv.y);
    float o2 = elu_f(acc2 * inv + bv.z);
    float o3 = elu_f(acc3 * inv + bv.w);
    if (!W3) {
        half4 hv;
        hv.a = __floats2half2_rn(o0, o1);
        hv.b = __floats2half2_rn(o2, o3);
        ((half4*)(Y + (size_t)n * 128))[l] = hv;
    } else {
        float4 wa = ((const float4*)W3)[l * 2];
        float4 wb = ((const float4*)W3)[l * 2 + 1];
        float p0 = o0 * wa.x + o1 * wa.z + o2 * wb.x + o3 * wb.z;
        float p1 = o0 * wa.y + o1 * wa.w + o2 * wb.y + o3 * wb.w;
        for (int off = 16; off > 0; off >>= 1) {
            p0 += __shfl_down(p0, off, 32);
            p1 += __shfl_down(p1, off, 32);
        }
        if (l == 0) {
            h3[n * 2 + 0] = p0;
            h3[n * 2 + 1] = p1;
            as3[n] = p0 * s3w[0] + p1 * s3w[1];
            ad3[n] = p0 * d3w[0] + p1 * d3w[1];
        }
    }
}

__device__ __forceinline__
void scan1_f(const int* __restrict__ counts, int* __restrict__ rp,
             int* __restrict__ bsums, int bx, int tid, int* lsum) {
    int base = bx * SCAN_B;
    int v[4]; int tsum = 0;
#pragma unroll
    for (int j = 0; j < 4; ++j) {
        int i = base + tid * 4 + j;
        v[j] = (i < NN) ? counts[i] : 0;
        tsum += v[j];
    }
    lsum[tid] = tsum;
    __syncthreads();
    for (int off = 1; off < 256; off <<= 1) {
        int t = (tid >= off) ? lsum[tid - off] : 0;
        __syncthreads();
        lsum[tid] += t;
        __syncthreads();
    }
    int excl = lsum[tid] - tsum;
#pragma unroll
    for (int j = 0; j < 4; ++j) {
        int i = base + tid * 4 + j;
        if (i < NN) rp[i] = excl;
        excl += v[j];
    }
    if (tid == 255) bsums[bx] = lsum[255];
}

__device__ __forceinline__
void scan23_f(int* __restrict__ rp, const int* __restrict__ bsums,
              int bx, int tid, int* psadd) {
    if (tid < 64) {
        int ln = tid;
        int v = (ln < NBLK) ? bsums[ln] : 0;
        for (int off = 1; off < 64; off <<= 1) {
            int t = __shfl_up(v, off, 64);
            if (ln >= off) v += t;
        }
        int srcl = (bx == 0) ? 0 : (bx - 1);
        int ex = __shfl(v, srcl, 64);
        if (ln == 0) *psadd = (bx == 0) ? 0 : ex;
        if (bx == 0 && ln == 63) rp[NN] = v;   // grand total (== ET)
    }
    __syncthreads();
    int add = *psadd;
    int base = bx * SCAN_B + tid * 4;
#pragma unroll
    for (int j = 0; j < 4; ++j) {
        int i = base + j;
        if (i < NN) rp[i] += add;
    }
}

__device__ __forceinline__
void l3_node(int n, const Params& p) {
    if (n >= NN) return;
    const float2* h2 = (const float2*)p.h3;
    float adn = p.d3v[n];
    float den = 0.f, a0 = 0.f, a1 = 0.f;
    int e = p.rp[n], end = p.rp[n + 1], last = end - 1;
    for (int base = e; base < end; base += 4) {
        int s[4]; float al[4]; float2 g[4];
#pragma unroll
        for (int j = 0; j < 4; ++j) {
            int i = base + j;
            s[j] = p.csr[i <= last ? i : last];
        }
#pragma unroll
        for (int j = 0; j < 4; ++j) al[j] = p.s3v[s[j]] + adn;
#pragma unroll
        for (int j = 0; j < 4; ++j) g[j] = h2[s[j]];
#pragma unroll
        for (int j = 0; j < 4; ++j) {
            float w = __expf(leaky(al[j]));
            w = (base + j <= last) ? w : 0.f;
            den += w;
            a0 += w * g[j].x;
            a1 += w * g[j].y;
        }
    }
    float o0 = a0 / den + p.b3[0];
    float o1 = a1 / den + p.b3[1];
    float m = fmaxf(o0, o1);
    float lse = m + logf(__expf(o0 - m) + __expf(o1 - m));
    p.out[n * 2 + 0] = o0 - lse;
    p.out[n * 2 + 1] = o1 - lse;
}

// ================= the persistent pipeline kernel =================
__global__ __launch_bounds__(256, 4)
void persist_k(Params p) {
    __shared__ int lsum[256];
    __shared__ int sadd;
    const int tid  = threadIdx.x;
    const int bid  = blockIdx.x;
    const int lane = tid & 63;
    const int wid  = tid >> 6;
    const int hw   = (lane >> 5);
    const int l    = lane & 31;

    // ---- P0: weight transposes + zero counts ----
    for (int i = bid * 256 + tid; i < 32768 + NN; i += GRID * 256) {
        if (i < 16384) {
            int k = i >> 7, n = i & 127;
            p.Wt1[n * 128 + k] = __float2half(p.W1[i]);
        } else if (i < 32768) {
            int j = i - 16384; int k = j >> 7, n = j & 127;
            p.Wt2[n * 128 + k] = __float2half(p.W2[j]);
        } else {
            p.counts[i - 32768] = 0;
        }
    }
    gsync(p.cnt, p.rel, 1);

    // ---- P1: gemm1 tiles [0,S1A) || hist ----
    for (int vb = bid; vb < S1A + HB; vb += GRID) {
        if (vb < S1A) {
            int row0 = vb * 64 + wid * 16;
            gemm_tile(p.x, nullptr, p.Wt1, p.hA, NN, row0, lane,
                      p.as1, p.ad1, p.asb, p.adb);
        } else {
            int i = (vb - S1A) * 256 + tid;
            if (i < ET) {
                int dst = (i < EE) ? p.ei[EE + i] : (i - EE);
                p.rank[i] = atomicAdd(&p.counts[dst], 1);
            }
        }
    }
    gsync(p.cnt, p.rel, 2);

    // ---- P2: scan1 || gemm1 [S1A,S1B) ----
    for (int vb = bid; vb < NBLK + (S1B - S1A); vb += GRID) {
        if (vb < NBLK) {
            scan1_f(p.counts, p.rp, p.bsums, vb, tid, lsum);
        } else {
            int row0 = (S1A + vb - NBLK) * 64 + wid * 16;
            gemm_tile(p.x, nullptr, p.Wt1, p.hA, NN, row0, lane,
                      p.as1, p.ad1, p.asb, p.adb);
        }
    }
    gsync(p.cnt, p.rel, 3);

    // ---- P3: scan23 || gemm1 [S1B,S1C) ----
    for (int vb = bid; vb < NBLK + (S1C - S1B); vb += GRID) {
        if (vb < NBLK) {
            scan23_f(p.rp, p.bsums, vb, tid, &sadd);
        } else {
            int row0 = (S1B + vb - NBLK) * 64 + wid * 16;
            gemm_tile(p.x, nullptr, p.Wt1, p.hA, NN, row0, lane,
                      p.as1, p.ad1, p.asb, p.adb);
        }
    }
    gsync(p.cnt, p.rel, 4);

    // ---- P4: scatter || gemm1 [S1C,GT1) ----
    for (int vb = bid; vb < HB + (GT1 - S1C); vb += GRID) {
        if (vb < HB) {
            int i = vb * 256 + tid;
            if (i < ET) {
                int src, dst;
                if (i < EE) { src = p.ei[i]; dst = p.ei[EE + i]; }
                else        { src = dst = i - EE; }
                p.csr[p.rp[dst] + p.rank[i]] = src;
            }
        } else {
            int row0 = (S1C + vb - HB) * 64 + wid * 16;
            if (row0 < NN)
                gemm_tile(p.x, nullptr, p.Wt1, p.hA, NN, row0, lane,
                          p.as1, p.ad1, p.asb, p.adb);
        }
    }
    gsync(p.cnt, p.rel, 5);

    // ---- P5: agg1 nodes [0, NSPL) ----
    for (int vb = bid; vb < ASPL; vb += GRID) {
        int n = vb * 8 + wid * 2 + hw;
        agg_node(n, l, p.hA, p.asb, p.adb, p.rp, p.csr, p.b1, p.hBh,
                 nullptr, nullptr, nullptr, nullptr, nullptr, nullptr);
    }
    gsync(p.cnt, p.rel, 6);

    // ---- P6: agg1 nodes [NSPL, NN) || gemm2 rows [0, NSPL) ----
    {
        const int A6 = AGG_VB - ASPL;   // 2154
        for (int vb = bid; vb < A6 + G2A; vb += GRID) {
            if (vb < A6) {
                int n = NSPL + vb * 8 + wid * 2 + hw;
                agg_node(n, l, p.hA, p.asb, p.adb, p.rp, p.csr, p.b1, p.hBh,
                         nullptr, nullptr, nullptr, nullptr, nullptr, nullptr);
            } else {
                int row0 = (vb - A6) * 64 + wid * 16;
                gemm_tile(nullptr, p.hBh, p.Wt2, p.hC, NN, row0, lane,
                          p.as2, p.ad2, p.asb2, p.adb2);
            }
        }
    }
    gsync(p.cnt, p.rel, 7);

    // ---- P7: gemm2 rows [NSPL, NN) ----
    for (int vb = bid; vb < GT1 - G2A; vb += GRID) {
        int row0 = (G2A + vb) * 64 + wid * 16;
        if (row0 < NN)
            gemm_tile(nullptr, p.hBh, p.Wt2, p.hC, NN, row0, lane,
                      p.as2, p.ad2, p.asb2, p.adb2);
    }
    gsync(p.cnt, p.rel, 8);

    // ---- P8: agg2 (+ fused layer-3 projection/logits) ----
    for (int vb = bid; vb < AGG_VB; vb += GRID) {
        int n = vb * 8 + wid * 2 + hw;
        agg_node(n, l, p.hC, p.asb2, p.adb2, p.rp, p.csr, p.b2, nullptr,
                 p.W3, p.s3w, p.d3w, p.h3, p.s3v, p.d3v);
    }
    gsync(p.cnt, p.rel, 9);

    // ---- P9: layer-3 aggregation + log_softmax ----
    for (int vb = bid; vb < 196; vb += GRID) {
        int n = vb * 256 + tid;
        l3_node(n, p);
    }
}

extern "C" void kernel_launch(void* const* d_in, const int* in_sizes, int n_in,
                              void* d_out, int out_size, void* d_ws, size_t ws_size,
                              hipStream_t stream) {
    char* ws = (char*)d_ws;
    size_t off = 0;
    auto alloc = [&](size_t bytes) -> char* {
        char* p = ws + off;
        off = (off + bytes + 255) & ~(size_t)255;
        return p;
    };
    int*    bar   = (int*)alloc(256);                       // cnt @0, rel @64
    __half* hA    = (__half*)alloc((size_t)NN * 128 * 2);   // gemm1 out (fp16)
    __half* hBh   = (__half*)alloc((size_t)NN * 128 * 2);   // agg1 out / gemm2 in
    __half* hC    = (__half*)alloc((size_t)NN * 128 * 2);   // gemm2 out (fp16)
    float* asb    = (float*)alloc((size_t)NN * 4 * 4);
    float* adb    = (float*)alloc((size_t)NN * 4 * 4);
    float* asb2   = (float*)alloc((size_t)NN * 4 * 4);
    float* adb2   = (float*)alloc((size_t)NN * 4 * 4);
    int*   rp     = (int*)alloc((size_t)(NN + 1) * 4);
    int*   counts = (int*)alloc((size_t)NN * 4);
    int*   csr    = (int*)alloc((size_t)ET * 4);
    int*   rank   = (int*)alloc((size_t)ET * 4);
    int*   bsums  = (int*)alloc((size_t)NBLK * 4);
    __half* Wt1   = (__half*)alloc(128 * 128 * 2);
    __half* Wt2   = (__half*)alloc(128 * 128 * 2);
    float* h3     = (float*)alloc((size_t)NN * 2 * 4);
    float* s3v    = (float*)alloc((size_t)NN * 4);
    float* d3v    = (float*)alloc((size_t)NN * 4);

    hipMemsetAsync(bar, 0, 256, stream);   // barrier state must start at 0

    Params p;
    p.x   = (const float*)d_in[0];
    p.ei  = (const int*)d_in[1];
    p.W1  = (const float*)d_in[2];
    p.as1 = (const float*)d_in[3];
    p.ad1 = (const float*)d_in[4];
    p.b1  = (const float*)d_in[5];
    p.W2  = (const float*)d_in[6];
    p.as2 = (const float*)d_in[7];
    p.ad2 = (const float*)d_in[8];
    p.b2  = (const float*)d_in[9];
    p.W3  = (const float*)d_in[10];
    p.s3w = (const float*)d_in[11];
    p.d3w = (const float*)d_in[12];
    p.b3  = (const float*)d_in[13];
    p.out = (float*)d_out;
    p.hA = hA; p.hBh = hBh; p.hC = hC; p.Wt1 = Wt1; p.Wt2 = Wt2;
    p.asb = asb; p.adb = adb; p.asb2 = asb2; p.adb2 = adb2;
    p.rp = rp; p.counts = counts; p.csr = csr; p.rank = rank; p.bsums = bsums;
    p.h3 = h3; p.s3v = s3v; p.d3v = d3v;
    p.cnt = bar; p.rel = bar + 16;

    persist_k<<<GRID, 256, 0, stream>>>(p);
}

// Round 4
// 1103.921 us; speedup vs baseline: 1.0604x; 1.0604x over previous
//
#include <hip/hip_runtime.h>
#include <hip/hip_fp16.h>

#define NN 50000
#define EE 800000
#define ET 850000          // EE + NN self-loops
#define NEG 0.2f
#define GRID 768
#define SCAN_B 1024
#define NBLK 49            // ceil(NN / SCAN_B)
#define GT1 782            // gemm 64-row tiles over 50000 rows
#define S1A 480            // gemm1 tiles in P1 (|| hist)
#define S1B 530            // .. through P2 (|| scan1)
#define S1C 580            // .. through P3 (|| scan23); rest in P4 (|| scatter)
#define HB 3321            // edge passes: ceil(ET/256) virtual blocks
#define AGG_VB 6250        // NN/8 agg virtual blocks
#define ASPL 4096          // agg1 split: vb [0,4096) = nodes [0,32768)
#define NSPL 32768
#define G2A 512            // gemm2 tiles covering rows [0,32768)

__device__ __forceinline__ float leaky(float x) { return fmaxf(x, NEG * x); }
__device__ __forceinline__ float elu_f(float x) { return x > 0.f ? x : expm1f(x); }

struct alignas(8) half4 { __half2 a, b; };

typedef _Float16 half8_t __attribute__((ext_vector_type(8)));
typedef float float4_t __attribute__((ext_vector_type(4)));

struct Params {
    const float *x; const int *ei;
    const float *W1, *as1, *ad1, *b1;
    const float *W2, *as2, *ad2, *b2;
    const float *W3, *s3w, *d3w, *b3;
    float *out;
    __half *hA, *hBh, *hC, *Wt1, *Wt2;
    float *asb, *adb, *asb2, *adb2;
    int *rp, *counts, *csr, *rank, *bsums;
    float *h3, *s3v, *d3v;
    int *cnt, *rel;
};

// ---- grid-wide barrier: all GRID blocks co-resident (launch_bounds(256,3)
// guarantees >=3 blocks/CU capacity; 768 = 3x256 CUs). Agent-scope atomics so
// the spin load bypasses the non-coherent per-XCD L2; __threadfence gives the
// device-scope release/acquire cache ops around the signal.
__device__ __forceinline__ void gsync(int* cnt, int* rel, int ph) {
    __syncthreads();
    if (threadIdx.x == 0) {
        __threadfence();   // release: write back this XCD's dirty lines
        int old = __hip_atomic_fetch_add(cnt, 1, __ATOMIC_ACQ_REL, __HIP_MEMORY_SCOPE_AGENT);
        if (old == GRID - 1) {
            __hip_atomic_store(cnt, 0, __ATOMIC_RELAXED, __HIP_MEMORY_SCOPE_AGENT);
            __hip_atomic_store(rel, ph, __ATOMIC_RELEASE, __HIP_MEMORY_SCOPE_AGENT);
        } else {
            while (__hip_atomic_load(rel, __ATOMIC_RELAXED, __HIP_MEMORY_SCOPE_AGENT) < ph)
                __builtin_amdgcn_s_sleep(8);
        }
        __threadfence();   // acquire: invalidate stale L1/L2
    }
    __syncthreads();
}

// ---- MFMA GEMM tile: 16 rows x 128 cols per wave, fused attention logits ----
__device__ __forceinline__
void gemm_tile(const float* __restrict__ Xf, const __half* __restrict__ Xh,
               const __half* __restrict__ Wt, __half* __restrict__ Yh,
               int nrows, int row0, int lane,
               const float* __restrict__ att_s, const float* __restrict__ att_d,
               float* __restrict__ asb, float* __restrict__ adb) {
    int n = lane & 15, quad = lane >> 4;
    float atts_r[8], attd_r[8];
#pragma unroll
    for (int t = 0; t < 8; ++t) {
        atts_r[t] = att_s[t * 16 + n];
        attd_r[t] = att_d[t * 16 + n];
    }
    float4_t acc[8];
#pragma unroll
    for (int t = 0; t < 8; ++t) acc[t] = (float4_t){0.f, 0.f, 0.f, 0.f};
    int rA = row0 + n; if (rA >= nrows) rA = nrows - 1;
#pragma unroll
    for (int ch = 0; ch < 4; ++ch) {
        half8_t a;
        if (Xh) {
            a = *(const half8_t*)(Xh + (size_t)rA * 128 + ch * 32 + quad * 8);
        } else {
            const float* xp = Xf + (size_t)rA * 128 + ch * 32 + quad * 8;
            float4 f0 = *(const float4*)xp;
            float4 f1 = *(const float4*)(xp + 4);
            a = (half8_t){(_Float16)f0.x, (_Float16)f0.y, (_Float16)f0.z, (_Float16)f0.w,
                          (_Float16)f1.x, (_Float16)f1.y, (_Float16)f1.z, (_Float16)f1.w};
        }
#pragma unroll
        for (int t = 0; t < 8; ++t) {
            half8_t b = *(const half8_t*)(Wt + (t * 16 + n) * 128 + ch * 32 + quad * 8);
            acc[t] = __builtin_amdgcn_mfma_f32_16x16x32_f16(a, b, acc[t], 0, 0, 0);
        }
    }
#pragma unroll
    for (int rg = 0; rg < 4; ++rg) {
        int row = row0 + quad * 4 + rg;
        if (row < nrows) {
            __half* yp = Yh + (size_t)row * 128 + n;
#pragma unroll
            for (int t = 0; t < 8; ++t)
                yp[t * 16] = __float2half(acc[t][rg]);
        }
    }
#pragma unroll
    for (int rg = 0; rg < 4; ++rg) {
        float ps[4], pd[4];
#pragma unroll
        for (int h = 0; h < 4; ++h) {
            ps[h] = acc[2*h][rg] * atts_r[2*h] + acc[2*h+1][rg] * atts_r[2*h+1];
            pd[h] = acc[2*h][rg] * attd_r[2*h] + acc[2*h+1][rg] * attd_r[2*h+1];
#pragma unroll
            for (int mask = 1; mask < 16; mask <<= 1) {
                ps[h] += __shfl_xor(ps[h], mask, 64);
                pd[h] += __shfl_xor(pd[h], mask, 64);
            }
        }
        int row = row0 + quad * 4 + rg;
        if (n == 0 && row < nrows) {
#pragma unroll
            for (int h = 0; h < 4; ++h) {
                asb[row * 4 + h] = ps[h];
                adb[row * 4 + h] = pd[h];
            }
        }
    }
}

// ---- per-node softmax + aggregation (half-wave = 32 lanes per node) ----
__device__ __forceinline__
void agg_node(int n, int l, const __half* __restrict__ Hh,
              const float* __restrict__ asb, const float* __restrict__ adb,
              const int* __restrict__ rp, const int* __restrict__ csr,
              const float* __restrict__ bias, __half* __restrict__ Y,
              const float* __restrict__ W3, const float* __restrict__ s3w,
              const float* __restrict__ d3w, float* __restrict__ h3,
              float* __restrict__ as3, float* __restrict__ ad3) {
    if (n >= NN) return;
    int hd = l >> 3;
    float ad = adb[n * 4 + hd];
    float acc0 = 0.f, acc1 = 0.f, acc2 = 0.f, acc3 = 0.f, den = 0.f;
    int e = rp[n], end = rp[n + 1], last = end - 1;
    for (int base = e; base < end; base += 8) {
        int s[8]; float a[8]; float2 hraw[8];
#pragma unroll
        for (int j = 0; j < 8; ++j) {
            int i = base + j;
            s[j] = csr[i <= last ? i : last];
        }
#pragma unroll
        for (int j = 0; j < 8; ++j) a[j] = asb[s[j] * 4 + hd] + ad;
#pragma unroll
        for (int j = 0; j < 8; ++j)
            hraw[j] = ((const float2*)(Hh + (size_t)s[j] * 128))[l];
#pragma unroll
        for (int j = 0; j < 8; ++j) {
            float w = __expf(leaky(a[j]));
            w = (base + j <= last) ? w : 0.f;
            den += w;
            const __half2* hp = (const __half2*)&hraw[j];
            float2 f01 = __half22float2(hp[0]);
            float2 f23 = __half22float2(hp[1]);
            acc0 += w * f01.x; acc1 += w * f01.y;
            acc2 += w * f23.x; acc3 += w * f23.y;
        }
    }
    float4 bv = ((const float4*)bias)[l];
    float inv = 1.f / den;
    float o0 = elu_f(acc0 * inv + bv.x);
    float o1 = elu_f(acc1 * inv + bv.y);
    float o2 = elu_f(acc2 * inv + bv.z);
    float o3 = elu_f(acc3 * inv + bv.w);
    if (!W3) {
        half4 hv;
        hv.a = __floats2half2_rn(o0, o1);
        hv.b = __floats2half2_rn(o2, o3);
        ((half4*)(Y + (size_t)n * 128))[l] = hv;
    } else {
        float4 wa = ((const float4*)W3)[l * 2];
        float4 wb = ((const float4*)W3)[l * 2 + 1];
        float p0 = o0 * wa.x + o1 * wa.z + o2 * wb.x + o3 * wb.z;
        float p1 = o0 * wa.y + o1 * wa.w + o2 * wb.y + o3 * wb.w;
        for (int off = 16; off > 0; off >>= 1) {
            p0 += __shfl_down(p0, off, 32);
            p1 += __shfl_down(p1, off, 32);
        }
        if (l == 0) {
            h3[n * 2 + 0] = p0;
            h3[n * 2 + 1] = p1;
            as3[n] = p0 * s3w[0] + p1 * s3w[1];
            ad3[n] = p0 * d3w[0] + p1 * d3w[1];
        }
    }
}

__device__ __forceinline__
void scan1_f(const int* __restrict__ counts, int* __restrict__ rp,
             int* __restrict__ bsums, int bx, int tid, int* lsum) {
    int base = bx * SCAN_B;
    int v[4]; int tsum = 0;
#pragma unroll
    for (int j = 0; j < 4; ++j) {
        int i = base + tid * 4 + j;
        v[j] = (i < NN) ? counts[i] : 0;
        tsum += v[j];
    }
    lsum[tid] = tsum;
    __syncthreads();
    for (int off = 1; off < 256; off <<= 1) {
        int t = (tid >= off) ? lsum[tid - off] : 0;
        __syncthreads();
        lsum[tid] += t;
        __syncthreads();
    }
    int excl = lsum[tid] - tsum;
#pragma unroll
    for (int j = 0; j < 4; ++j) {
        int i = base + tid * 4 + j;
        if (i < NN) rp[i] = excl;
        excl += v[j];
    }
    if (tid == 255) bsums[bx] = lsum[255];
}

__device__ __forceinline__
void scan23_f(int* __restrict__ rp, const int* __restrict__ bsums,
              int bx, int tid, int* psadd) {
    if (tid < 64) {
        int ln = tid;
        int v = (ln < NBLK) ? bsums[ln] : 0;
        for (int off = 1; off < 64; off <<= 1) {
            int t = __shfl_up(v, off, 64);
            if (ln >= off) v += t;
        }
        int srcl = (bx == 0) ? 0 : (bx - 1);
        int ex = __shfl(v, srcl, 64);
        if (ln == 0) *psadd = (bx == 0) ? 0 : ex;
        if (bx == 0 && ln == 63) rp[NN] = v;   // grand total (== ET)
    }
    __syncthreads();
    int add = *psadd;
    int base = bx * SCAN_B + tid * 4;
#pragma unroll
    for (int j = 0; j < 4; ++j) {
        int i = base + j;
        if (i < NN) rp[i] += add;
    }
}

__device__ __forceinline__
void l3_node(int n, const Params& p) {
    if (n >= NN) return;
    const float2* h2 = (const float2*)p.h3;
    float adn = p.d3v[n];
    float den = 0.f, a0 = 0.f, a1 = 0.f;
    int e = p.rp[n], end = p.rp[n + 1], last = end - 1;
    for (int base = e; base < end; base += 4) {
        int s[4]; float al[4]; float2 g[4];
#pragma unroll
        for (int j = 0; j < 4; ++j) {
            int i = base + j;
            s[j] = p.csr[i <= last ? i : last];
        }
#pragma unroll
        for (int j = 0; j < 4; ++j) al[j] = p.s3v[s[j]] + adn;
#pragma unroll
        for (int j = 0; j < 4; ++j) g[j] = h2[s[j]];
#pragma unroll
        for (int j = 0; j < 4; ++j) {
            float w = __expf(leaky(al[j]));
            w = (base + j <= last) ? w : 0.f;
            den += w;
            a0 += w * g[j].x;
            a1 += w * g[j].y;
        }
    }
    float o0 = a0 / den + p.b3[0];
    float o1 = a1 / den + p.b3[1];
    float m = fmaxf(o0, o1);
    float lse = m + logf(__expf(o0 - m) + __expf(o1 - m));
    p.out[n * 2 + 0] = o0 - lse;
    p.out[n * 2 + 1] = o1 - lse;
}

// ================= the persistent pipeline kernel =================
// (256,3): 3 waves/EU min -> VGPR cap ~170 (>= the ~110 gemm_tile needs, so
// no spills), and 3 blocks/CU * 256 CU = 768 = GRID stays fully co-resident.
__global__ __launch_bounds__(256, 3)
void persist_k(Params p) {
    __shared__ int lsum[256];
    __shared__ int sadd;
    const int tid  = threadIdx.x;
    const int bid  = blockIdx.x;
    const int lane = tid & 63;
    const int wid  = tid >> 6;
    const int hw   = (lane >> 5);
    const int l    = lane & 31;

    // ---- P0: weight transposes + zero counts ----
    for (int i = bid * 256 + tid; i < 32768 + NN; i += GRID * 256) {
        if (i < 16384) {
            int k = i >> 7, n = i & 127;
            p.Wt1[n * 128 + k] = __float2half(p.W1[i]);
        } else if (i < 32768) {
            int j = i - 16384; int k = j >> 7, n = j & 127;
            p.Wt2[n * 128 + k] = __float2half(p.W2[j]);
        } else {
            p.counts[i - 32768] = 0;
        }
    }
    gsync(p.cnt, p.rel, 1);

    // ---- P1: gemm1 tiles [0,S1A) || hist ----
    for (int vb = bid; vb < S1A + HB; vb += GRID) {
        if (vb < S1A) {
            int row0 = vb * 64 + wid * 16;
            gemm_tile(p.x, nullptr, p.Wt1, p.hA, NN, row0, lane,
                      p.as1, p.ad1, p.asb, p.adb);
        } else {
            int i = (vb - S1A) * 256 + tid;
            if (i < ET) {
                int dst = (i < EE) ? p.ei[EE + i] : (i - EE);
                p.rank[i] = atomicAdd(&p.counts[dst], 1);
            }
        }
    }
    gsync(p.cnt, p.rel, 2);

    // ---- P2: scan1 || gemm1 [S1A,S1B) ----
    for (int vb = bid; vb < NBLK + (S1B - S1A); vb += GRID) {
        if (vb < NBLK) {
            scan1_f(p.counts, p.rp, p.bsums, vb, tid, lsum);
        } else {
            int row0 = (S1A + vb - NBLK) * 64 + wid * 16;
            gemm_tile(p.x, nullptr, p.Wt1, p.hA, NN, row0, lane,
                      p.as1, p.ad1, p.asb, p.adb);
        }
    }
    gsync(p.cnt, p.rel, 3);

    // ---- P3: scan23 || gemm1 [S1B,S1C) ----
    for (int vb = bid; vb < NBLK + (S1C - S1B); vb += GRID) {
        if (vb < NBLK) {
            scan23_f(p.rp, p.bsums, vb, tid, &sadd);
        } else {
            int row0 = (S1B + vb - NBLK) * 64 + wid * 16;
            gemm_tile(p.x, nullptr, p.Wt1, p.hA, NN, row0, lane,
                      p.as1, p.ad1, p.asb, p.adb);
        }
    }
    gsync(p.cnt, p.rel, 4);

    // ---- P4: scatter || gemm1 [S1C,GT1) ----
    for (int vb = bid; vb < HB + (GT1 - S1C); vb += GRID) {
        if (vb < HB) {
            int i = vb * 256 + tid;
            if (i < ET) {
                int src, dst;
                if (i < EE) { src = p.ei[i]; dst = p.ei[EE + i]; }
                else        { src = dst = i - EE; }
                p.csr[p.rp[dst] + p.rank[i]] = src;
            }
        } else {
            int row0 = (S1C + vb - HB) * 64 + wid * 16;
            if (row0 < NN)
                gemm_tile(p.x, nullptr, p.Wt1, p.hA, NN, row0, lane,
                          p.as1, p.ad1, p.asb, p.adb);
        }
    }
    gsync(p.cnt, p.rel, 5);

    // ---- P5: agg1 nodes [0, NSPL) ----
    for (int vb = bid; vb < ASPL; vb += GRID) {
        int n = vb * 8 + wid * 2 + hw;
        agg_node(n, l, p.hA, p.asb, p.adb, p.rp, p.csr, p.b1, p.hBh,
                 nullptr, nullptr, nullptr, nullptr, nullptr, nullptr);
    }
    gsync(p.cnt, p.rel, 6);

    // ---- P6: agg1 nodes [NSPL, NN) || gemm2 rows [0, NSPL) ----
    {
        const int A6 = AGG_VB - ASPL;   // 2154
        for (int vb = bid; vb < A6 + G2A; vb += GRID) {
            if (vb < A6) {
                int n = NSPL + vb * 8 + wid * 2 + hw;
                agg_node(n, l, p.hA, p.asb, p.adb, p.rp, p.csr, p.b1, p.hBh,
                         nullptr, nullptr, nullptr, nullptr, nullptr, nullptr);
            } else {
                int row0 = (vb - A6) * 64 + wid * 16;
                gemm_tile(nullptr, p.hBh, p.Wt2, p.hC, NN, row0, lane,
                          p.as2, p.ad2, p.asb2, p.adb2);
            }
        }
    }
    gsync(p.cnt, p.rel, 7);

    // ---- P7: gemm2 rows [NSPL, NN) ----
    for (int vb = bid; vb < GT1 - G2A; vb += GRID) {
        int row0 = (G2A + vb) * 64 + wid * 16;
        if (row0 < NN)
            gemm_tile(nullptr, p.hBh, p.Wt2, p.hC, NN, row0, lane,
                      p.as2, p.ad2, p.asb2, p.adb2);
    }
    gsync(p.cnt, p.rel, 8);

    // ---- P8: agg2 (+ fused layer-3 projection/logits) ----
    for (int vb = bid; vb < AGG_VB; vb += GRID) {
        int n = vb * 8 + wid * 2 + hw;
        agg_node(n, l, p.hC, p.asb2, p.adb2, p.rp, p.csr, p.b2, nullptr,
                 p.W3, p.s3w, p.d3w, p.h3, p.s3v, p.d3v);
    }
    gsync(p.cnt, p.rel, 9);

    // ---- P9: layer-3 aggregation + log_softmax ----
    for (int vb = bid; vb < 196; vb += GRID) {
        int n = vb * 256 + tid;
        l3_node(n, p);
    }
}

extern "C" void kernel_launch(void* const* d_in, const int* in_sizes, int n_in,
                              void* d_out, int out_size, void* d_ws, size_t ws_size,
                              hipStream_t stream) {
    char* ws = (char*)d_ws;
    size_t off = 0;
    auto alloc = [&](size_t bytes) -> char* {
        char* p = ws + off;
        off = (off + bytes + 255) & ~(size_t)255;
        return p;
    };
    int*    bar   = (int*)alloc(256);                       // cnt @0, rel @64
    __half* hA    = (__half*)alloc((size_t)NN * 128 * 2);   // gemm1 out (fp16)
    __half* hBh   = (__half*)alloc((size_t)NN * 128 * 2);   // agg1 out / gemm2 in
    __half* hC    = (__half*)alloc((size_t)NN * 128 * 2);   // gemm2 out (fp16)
    float* asb    = (float*)alloc((size_t)NN * 4 * 4);
    float* adb    = (float*)alloc((size_t)NN * 4 * 4);
    float* asb2   = (float*)alloc((size_t)NN * 4 * 4);
    float* adb2   = (float*)alloc((size_t)NN * 4 * 4);
    int*   rp     = (int*)alloc((size_t)(NN + 1) * 4);
    int*   counts = (int*)alloc((size_t)NN * 4);
    int*   csr    = (int*)alloc((size_t)ET * 4);
    int*   rank   = (int*)alloc((size_t)ET * 4);
    int*   bsums  = (int*)alloc((size_t)NBLK * 4);
    __half* Wt1   = (__half*)alloc(128 * 128 * 2);
    __half* Wt2   = (__half*)alloc(128 * 128 * 2);
    float* h3     = (float*)alloc((size_t)NN * 2 * 4);
    float* s3v    = (float*)alloc((size_t)NN * 4);
    float* d3v    = (float*)alloc((size_t)NN * 4);

    hipMemsetAsync(bar, 0, 256, stream);   // barrier state must start at 0

    Params p;
    p.x   = (const float*)d_in[0];
    p.ei  = (const int*)d_in[1];
    p.W1  = (const float*)d_in[2];
    p.as1 = (const float*)d_in[3];
    p.ad1 = (const float*)d_in[4];
    p.b1  = (const float*)d_in[5];
    p.W2  = (const float*)d_in[6];
    p.as2 = (const float*)d_in[7];
    p.ad2 = (const float*)d_in[8];
    p.b2  = (const float*)d_in[9];
    p.W3  = (const float*)d_in[10];
    p.s3w = (const float*)d_in[11];
    p.d3w = (const float*)d_in[12];
    p.b3  = (const float*)d_in[13];
    p.out = (float*)d_out;
    p.hA = hA; p.hBh = hBh; p.hC = hC; p.Wt1 = Wt1; p.Wt2 = Wt2;
    p.asb = asb; p.adb = adb; p.asb2 = asb2; p.adb2 = adb2;
    p.rp = rp; p.counts = counts; p.csr = csr; p.rank = rank; p.bsums = bsums;
    p.h3 = h3; p.s3v = s3v; p.d3v = d3v;
    p.cnt = bar; p.rel = bar + 16;

    persist_k<<<GRID, 256, 0, stream>>>(p);
}

// Round 5
// 271.503 us; speedup vs baseline: 4.3116x; 4.0660x over previous
//
#include <hip/hip_runtime.h>
#include <hip/hip_fp16.h>

#define NN 50000
#define EE 800000
#define ET 850000          // EE + NN self-loops
#define NEG 0.2f
#define SCAN_B 1024
#define NBLK ((NN + SCAN_B - 1) / SCAN_B)   // 49
#define GHALF 391          // gemm1 blocks per mega phase: 391*64 = 25024 rows
#define RHALF 25024
#define HIST_BLKS ((ET + 255) / 256)        // 3321
#define NSPL 39040         // agg1a covers nodes [0, NSPL)
#define A1A_VB 4880        // NSPL / 8
#define A1B_VB 1370        // (NN - NSPL) / 8
#define G2A 610            // gemm2 64-row blocks covering rows [0, NSPL)
#define G2B 172            // remaining gemm2 blocks

__device__ __forceinline__ float leaky(float x) { return fmaxf(x, NEG * x); }
__device__ __forceinline__ float elu_f(float x) { return x > 0.f ? x : expm1f(x); }

struct alignas(8) half4 { __half2 a, b; };

typedef _Float16 half8_t __attribute__((ext_vector_type(8)));
typedef float float4_t __attribute__((ext_vector_type(4)));

// ---- MFMA GEMM tile: 16 rows x 128 cols per wave, fused attention logits ----
__device__ __forceinline__
void gemm_tile(const float* __restrict__ Xf, const __half* __restrict__ Xh,
               const __half* __restrict__ Wt, __half* __restrict__ Yh,
               int nrows, int row0, int lane,
               const float* __restrict__ att_s, const float* __restrict__ att_d,
               float* __restrict__ asb, float* __restrict__ adb) {
    int n = lane & 15, quad = lane >> 4;
    float atts_r[8], attd_r[8];
#pragma unroll
    for (int t = 0; t < 8; ++t) {
        atts_r[t] = att_s[t * 16 + n];
        attd_r[t] = att_d[t * 16 + n];
    }
    float4_t acc[8];
#pragma unroll
    for (int t = 0; t < 8; ++t) acc[t] = (float4_t){0.f, 0.f, 0.f, 0.f};
    int rA = row0 + n; if (rA >= nrows) rA = nrows - 1;
#pragma unroll
    for (int ch = 0; ch < 4; ++ch) {
        half8_t a;
        if (Xh) {
            a = *(const half8_t*)(Xh + (size_t)rA * 128 + ch * 32 + quad * 8);
        } else {
            const float* xp = Xf + (size_t)rA * 128 + ch * 32 + quad * 8;
            float4 f0 = *(const float4*)xp;
            float4 f1 = *(const float4*)(xp + 4);
            a = (half8_t){(_Float16)f0.x, (_Float16)f0.y, (_Float16)f0.z, (_Float16)f0.w,
                          (_Float16)f1.x, (_Float16)f1.y, (_Float16)f1.z, (_Float16)f1.w};
        }
#pragma unroll
        for (int t = 0; t < 8; ++t) {
            half8_t b = *(const half8_t*)(Wt + (t * 16 + n) * 128 + ch * 32 + quad * 8);
            acc[t] = __builtin_amdgcn_mfma_f32_16x16x32_f16(a, b, acc[t], 0, 0, 0);
        }
    }
    // C store (fp16): col = t*16 + n, row = quad*4 + rg
#pragma unroll
    for (int rg = 0; rg < 4; ++rg) {
        int row = row0 + quad * 4 + rg;
        if (row < nrows) {
            __half* yp = Yh + (size_t)row * 128 + n;
#pragma unroll
            for (int t = 0; t < 8; ++t)
                yp[t * 16] = __float2half(acc[t][rg]);
        }
    }
    // fused alpha: reduce acc * att over the 16 col-lanes of each quad
#pragma unroll
    for (int rg = 0; rg < 4; ++rg) {
        float ps[4], pd[4];
#pragma unroll
        for (int h = 0; h < 4; ++h) {
            ps[h] = acc[2*h][rg] * atts_r[2*h] + acc[2*h+1][rg] * atts_r[2*h+1];
            pd[h] = acc[2*h][rg] * attd_r[2*h] + acc[2*h+1][rg] * attd_r[2*h+1];
#pragma unroll
            for (int mask = 1; mask < 16; mask <<= 1) {
                ps[h] += __shfl_xor(ps[h], mask, 64);
                pd[h] += __shfl_xor(pd[h], mask, 64);
            }
        }
        int row = row0 + quad * 4 + rg;
        if (n == 0 && row < nrows) {
#pragma unroll
            for (int h = 0; h < 4; ++h) {
                asb[row * 4 + h] = ps[h];
                adb[row * 4 + h] = pd[h];
            }
        }
    }
}

// ---- per-node softmax + aggregation (half-wave = 32 lanes per node) ----
__device__ __forceinline__
void agg_node(int n, int l, const __half* __restrict__ Hh,
              const float* __restrict__ asb, const float* __restrict__ adb,
              const int* __restrict__ rp, const int* __restrict__ csr,
              const float* __restrict__ bias, __half* __restrict__ Y,
              const float* __restrict__ W3, const float* __restrict__ s3w,
              const float* __restrict__ d3w, float* __restrict__ h3,
              float* __restrict__ as3, float* __restrict__ ad3) {
    if (n >= NN) return;
    int hd = l >> 3;
    float ad = adb[n * 4 + hd];
    float acc0 = 0.f, acc1 = 0.f, acc2 = 0.f, acc3 = 0.f, den = 0.f;
    int e = rp[n], end = rp[n + 1], last = end - 1;
    for (int base = e; base < end; base += 8) {
        int s[8]; float a[8]; float2 hraw[8];
#pragma unroll
        for (int j = 0; j < 8; ++j) {
            int i = base + j;
            s[j] = csr[i <= last ? i : last];
        }
#pragma unroll
        for (int j = 0; j < 8; ++j) a[j] = asb[s[j] * 4 + hd] + ad;
#pragma unroll
        for (int j = 0; j < 8; ++j)
            hraw[j] = ((const float2*)(Hh + (size_t)s[j] * 128))[l];
#pragma unroll
        for (int j = 0; j < 8; ++j) {
            float w = __expf(leaky(a[j]));
            w = (base + j <= last) ? w : 0.f;
            den += w;
            const __half2* hp = (const __half2*)&hraw[j];
            float2 f01 = __half22float2(hp[0]);
            float2 f23 = __half22float2(hp[1]);
            acc0 += w * f01.x; acc1 += w * f01.y;
            acc2 += w * f23.x; acc3 += w * f23.y;
        }
    }
    float4 bv = ((const float4*)bias)[l];
    float inv = 1.f / den;
    float o0 = elu_f(acc0 * inv + bv.x);
    float o1 = elu_f(acc1 * inv + bv.y);
    float o2 = elu_f(acc2 * inv + bv.z);
    float o3 = elu_f(acc3 * inv + bv.w);
    if (!W3) {
        half4 hv;
        hv.a = __floats2half2_rn(o0, o1);
        hv.b = __floats2half2_rn(o2, o3);
        ((half4*)(Y + (size_t)n * 128))[l] = hv;
    } else {
        float4 wa = ((const float4*)W3)[l * 2];
        float4 wb = ((const float4*)W3)[l * 2 + 1];
        float p0 = o0 * wa.x + o1 * wa.z + o2 * wb.x + o3 * wb.z;
        float p1 = o0 * wa.y + o1 * wa.w + o2 * wb.y + o3 * wb.w;
        for (int off = 16; off > 0; off >>= 1) {
            p0 += __shfl_down(p0, off, 32);
            p1 += __shfl_down(p1, off, 32);
        }
        if (l == 0) {
            h3[n * 2 + 0] = p0;
            h3[n * 2 + 1] = p1;
            as3[n] = p0 * s3w[0] + p1 * s3w[1];
            ad3[n] = p0 * d3w[0] + p1 * d3w[1];
        }
    }
}

// plain GEMM launch (block = 64 rows), with block offset for partial ranges
__global__ __launch_bounds__(256)
void gemm_mfma_k(const float* __restrict__ Xf, const __half* __restrict__ Xh,
                 const __half* __restrict__ Wt, __half* __restrict__ Yh, int nrows,
                 int blk0,
                 const float* __restrict__ att_s, const float* __restrict__ att_d,
                 float* __restrict__ asb, float* __restrict__ adb) {
    int lane = threadIdx.x & 63;
    int wid  = threadIdx.x >> 6;
    int row0 = ((blk0 + blockIdx.x) * 4 + wid) * 16;
    if (row0 < nrows)
        gemm_tile(Xf, Xh, Wt, Yh, nrows, row0, lane, att_s, att_d, asb, adb);
}

// ---- mega kernel 1: gemm1-half (blocks [0,GHALF)) + edge pass (hist/scatter) ----
__global__ __launch_bounds__(256)
void mega_k(const float* __restrict__ Xf, const __half* __restrict__ Wt,
            __half* __restrict__ Yh, int rowBase,
            const float* __restrict__ att_s, const float* __restrict__ att_d,
            float* __restrict__ asb, float* __restrict__ adb,
            int mode,                           // 0 = hist, 1 = scatter
            const int* __restrict__ ei, int* __restrict__ counts,
            int* __restrict__ rank, const int* __restrict__ rp,
            int* __restrict__ csr) {
    int b = blockIdx.x;
    if (b < GHALF) {
        int lane = threadIdx.x & 63;
        int wid  = threadIdx.x >> 6;
        int row0 = rowBase + (b * 4 + wid) * 16;
        if (row0 < NN)
            gemm_tile(Xf, nullptr, Wt, Yh, NN, row0, lane, att_s, att_d, asb, adb);
    } else {
        int i = (b - GHALF) * 256 + threadIdx.x;
        if (i < ET) {
            if (mode == 0) {
                int dst = (i < EE) ? ei[EE + i] : (i - EE);
                rank[i] = atomicAdd(&counts[dst], 1);
            } else {
                int src, dst;
                if (i < EE) { src = ei[i]; dst = ei[EE + i]; }
                else        { src = dst = i - EE; }
                csr[rp[dst] + rank[i]] = src;
            }
        }
    }
}

// ---- mega kernel 2: agg1 tail (nodes [NSPL,NN)) || gemm2 rows [0,NSPL) ----
__global__ __launch_bounds__(256)
void mega2_k(const __half* __restrict__ hA, const float* __restrict__ asb,
             const float* __restrict__ adb, const int* __restrict__ rp,
             const int* __restrict__ csr, const float* __restrict__ b1,
             __half* __restrict__ hBh,
             const __half* __restrict__ Wt2, __half* __restrict__ hC,
             const float* __restrict__ as2, const float* __restrict__ ad2,
             float* __restrict__ asb2, float* __restrict__ adb2) {
    int b = blockIdx.x;
    int lane = threadIdx.x & 63;
    if (b < A1B_VB) {
        int hw = lane >> 5;
        int l  = lane & 31;
        int n = NSPL + b * 8 + (threadIdx.x >> 6) * 2 + hw;
        agg_node(n, l, hA, asb, adb, rp, csr, b1, hBh,
                 nullptr, nullptr, nullptr, nullptr, nullptr, nullptr);
    } else {
        int g = b - A1B_VB;                 // [0, G2A)
        int wid = threadIdx.x >> 6;
        int row0 = (g * 4 + wid) * 16;      // < NSPL, all inputs ready (agg1a)
        gemm_tile(nullptr, hBh, Wt2, hC, NN, row0, lane, as2, ad2, asb2, adb2);
    }
}

// ---- prep: transpose W1,W2 (fp32 k-major -> fp16 n-major) + zero counts ----
__global__ void prep_k(const float* __restrict__ W1, __half* __restrict__ Wt1,
                       const float* __restrict__ W2, __half* __restrict__ Wt2,
                       int* __restrict__ counts) {
    int i = blockIdx.x * 256 + threadIdx.x;
    if (i < 16384) {
        int k = i >> 7, n = i & 127;
        Wt1[n * 128 + k] = __float2half(W1[i]);
    } else if (i < 32768) {
        int j = i - 16384;
        int k = j >> 7, n = j & 127;
        Wt2[n * 128 + k] = __float2half(W2[j]);
    } else {
        int j = i - 32768;
        if (j < NN) counts[j] = 0;
    }
}

// ---------------- CSR scans ----------------
__global__ void scan1_k(const int* __restrict__ counts, int* __restrict__ rp,
                        int* __restrict__ bsums) {
    __shared__ int lsum[256];
    int base = blockIdx.x * SCAN_B;
    int v[4];
    int tsum = 0;
#pragma unroll
    for (int j = 0; j < 4; ++j) {
        int i = base + threadIdx.x * 4 + j;
        v[j] = (i < NN) ? counts[i] : 0;
        tsum += v[j];
    }
    lsum[threadIdx.x] = tsum;
    __syncthreads();
    for (int off = 1; off < 256; off <<= 1) {
        int t = (threadIdx.x >= off) ? lsum[threadIdx.x - off] : 0;
        __syncthreads();
        lsum[threadIdx.x] += t;
        __syncthreads();
    }
    int excl = lsum[threadIdx.x] - tsum;
#pragma unroll
    for (int j = 0; j < 4; ++j) {
        int i = base + threadIdx.x * 4 + j;
        if (i < NN) rp[i] = excl;
        excl += v[j];
    }
    if (threadIdx.x == 255) bsums[blockIdx.x] = lsum[255];
}

// merged scan2+scan3: every block redundantly scans the 49 block sums (196 B)
__global__ void scan23_k(int* __restrict__ rp, const int* __restrict__ bsums) {
    __shared__ int sadd;
    int bx = blockIdx.x;
    if (threadIdx.x < 64) {
        int lane = threadIdx.x;
        int v = (lane < NBLK) ? bsums[lane] : 0;
        for (int off = 1; off < 64; off <<= 1) {
            int t = __shfl_up(v, off, 64);
            if (lane >= off) v += t;
        }
        int srcl = (bx == 0) ? 0 : (bx - 1);
        int ex = __shfl(v, srcl, 64);     // inclusive sum at lane bx-1
        if (lane == 0) sadd = (bx == 0) ? 0 : ex;
        if (bx == 0 && lane == 63) rp[NN] = v;   // grand total (== ET)
    }
    __syncthreads();
    int add = sadd;
    int base = bx * SCAN_B + threadIdx.x * 4;
#pragma unroll
    for (int j = 0; j < 4; ++j) {
        int i = base + j;
        if (i < NN) rp[i] += add;
    }
}

// ---- standalone agg launch (node range via nb0 + grid size) ----
__global__ __launch_bounds__(256)
void agg_k(int nb0, const __half* __restrict__ Hh, const float* __restrict__ asb,
           const float* __restrict__ adb, const int* __restrict__ rp,
           const int* __restrict__ csr, const float* __restrict__ bias,
           __half* __restrict__ Y,
           const float* __restrict__ W3, const float* __restrict__ s3w,
           const float* __restrict__ d3w, float* __restrict__ h3,
           float* __restrict__ as3, float* __restrict__ ad3) {
    int lane = threadIdx.x & 63;
    int hw = lane >> 5;
    int l  = lane & 31;
    int n = nb0 + blockIdx.x * 8 + (threadIdx.x >> 6) * 2 + hw;
    agg_node(n, l, Hh, asb, adb, rp, csr, bias, Y,
             W3, s3w, d3w, h3, as3, ad3);
}

// ---- layer-3 aggregation + log_softmax ----
__global__ void l3agg_k(const float* __restrict__ h3, const float* __restrict__ as3,
                        const float* __restrict__ ad3, const int* __restrict__ rp,
                        const int* __restrict__ csr, const float* __restrict__ b3,
                        float* __restrict__ out) {
    int n = blockIdx.x * blockDim.x + threadIdx.x;
    if (n >= NN) return;
    const float2* h2 = (const float2*)h3;
    float adn = ad3[n];
    float den = 0.f, a0 = 0.f, a1 = 0.f;
    int e = rp[n], end = rp[n + 1], last = end - 1;
    for (int base = e; base < end; base += 4) {
        int s[4]; float al[4]; float2 g[4];
#pragma unroll
        for (int j = 0; j < 4; ++j) {
            int i = base + j;
            s[j] = csr[i <= last ? i : last];
        }
#pragma unroll
        for (int j = 0; j < 4; ++j) al[j] = as3[s[j]] + adn;
#pragma unroll
        for (int j = 0; j < 4; ++j) g[j] = h2[s[j]];
#pragma unroll
        for (int j = 0; j < 4; ++j) {
            float w = __expf(leaky(al[j]));
            w = (base + j <= last) ? w : 0.f;
            den += w;
            a0 += w * g[j].x;
            a1 += w * g[j].y;
        }
    }
    float o0 = a0 / den + b3[0];
    float o1 = a1 / den + b3[1];
    float m = fmaxf(o0, o1);
    float lse = m + logf(__expf(o0 - m) + __expf(o1 - m));
    out[n * 2 + 0] = o0 - lse;
    out[n * 2 + 1] = o1 - lse;
}

extern "C" void kernel_launch(void* const* d_in, const int* in_sizes, int n_in,
                              void* d_out, int out_size, void* d_ws, size_t ws_size,
                              hipStream_t stream) {
    const float* x   = (const float*)d_in[0];
    const int*   ei  = (const int*)d_in[1];
    const float* W1  = (const float*)d_in[2];
    const float* as1 = (const float*)d_in[3];
    const float* ad1 = (const float*)d_in[4];
    const float* b1  = (const float*)d_in[5];
    const float* W2  = (const float*)d_in[6];
    const float* as2 = (const float*)d_in[7];
    const float* ad2 = (const float*)d_in[8];
    const float* b2  = (const float*)d_in[9];
    const float* W3  = (const float*)d_in[10];
    const float* s3w = (const float*)d_in[11];
    const float* d3w = (const float*)d_in[12];
    const float* b3  = (const float*)d_in[13];
    float* out = (float*)d_out;

    char* ws = (char*)d_ws;
    size_t off = 0;
    auto alloc = [&](size_t bytes) -> char* {
        char* p = ws + off;
        off = (off + bytes + 255) & ~(size_t)255;
        return p;
    };
    __half* hA    = (__half*)alloc((size_t)NN * 128 * 2);   // gemm1 out (fp16)
    __half* hBh   = (__half*)alloc((size_t)NN * 128 * 2);   // agg1 out / gemm2 in
    __half* hC    = (__half*)alloc((size_t)NN * 128 * 2);   // gemm2 out
    float* asb    = (float*)alloc((size_t)NN * 4 * 4);
    float* adb    = (float*)alloc((size_t)NN * 4 * 4);
    float* asb2   = (float*)alloc((size_t)NN * 4 * 4);
    float* adb2   = (float*)alloc((size_t)NN * 4 * 4);
    int*   rp     = (int*)alloc((size_t)(NN + 1) * 4);
    int*   counts = (int*)alloc((size_t)NN * 4);
    int*   csr    = (int*)alloc((size_t)ET * 4);
    int*   rank   = (int*)alloc((size_t)ET * 4);
    int*   bsums  = (int*)alloc((size_t)NBLK * 4);
    __half* Wt1   = (__half*)alloc(128 * 128 * 2);
    __half* Wt2   = (__half*)alloc(128 * 128 * 2);
    float* h3     = (float*)alloc((size_t)NN * 2 * 4);
    float* s3    = (float*)alloc((size_t)NN * 4);
    float* d3    = (float*)alloc((size_t)NN * 4);

    // 1) weight transposes + zero counts
    prep_k<<<(32768 + NN + 255) / 256, 256, 0, stream>>>(W1, Wt1, W2, Wt2, counts);

    // 2) megaA: gemm1 rows [0, 25024) || hist
    mega_k<<<GHALF + HIST_BLKS, 256, 0, stream>>>(x, Wt1, hA, 0, as1, ad1, asb, adb,
                                                  0, ei, counts, rank, nullptr, nullptr);

    // 3-4) scans (rp = exclusive prefix of counts)
    scan1_k<<<NBLK, 256, 0, stream>>>(counts, rp, bsums);
    scan23_k<<<NBLK, 256, 0, stream>>>(rp, bsums);

    // 5) megaB: gemm1 rows [25024, 50000) || scatter
    mega_k<<<GHALF + HIST_BLKS, 256, 0, stream>>>(x, Wt1, hA, RHALF, as1, ad1, asb, adb,
                                                  1, ei, counts, rank, rp, csr);

    // 6) agg1a: layer-1 softmax/aggregate, nodes [0, NSPL) -> hBh
    agg_k<<<A1A_VB, 256, 0, stream>>>(0, hA, asb, adb, rp, csr, b1, hBh,
                                      nullptr, nullptr, nullptr,
                                      nullptr, nullptr, nullptr);

    // 7) mega2: agg1 tail [NSPL, NN) || gemm2 rows [0, NSPL) (fused alpha2)
    mega2_k<<<A1B_VB + G2A, 256, 0, stream>>>(hA, asb, adb, rp, csr, b1, hBh,
                                              Wt2, hC, as2, ad2, asb2, adb2);

    // 8) gemm2b: rows [NSPL, 50000)
    gemm_mfma_k<<<G2B, 256, 0, stream>>>(nullptr, hBh, Wt2, hC, NN, G2A,
                                         as2, ad2, asb2, adb2);

    // 9) agg2 (+ fused layer-3 projection/logits)
    agg_k<<<(NN + 7) / 8, 256, 0, stream>>>(0, hC, asb2, adb2, rp, csr, b2, nullptr,
                                            W3, s3w, d3w, h3, s3, d3);

    // 10) layer-3 aggregation + log_softmax
    l3agg_k<<<(NN + 255) / 256, 256, 0, stream>>>(h3, s3, d3, rp, csr, b3, out);
}